// Round 5
// baseline (66.057 us; speedup 1.0000x reference)
//
#include <hip/hip_runtime.h>

// BezierGlyph: 512x512 pixels vs 512 bezier samples (16 strokes x 32).
// min_dist = -LSE(-256*d)/256 ; out = 1/(1+exp((0.04-min_dist)*200))
//
// v5: two-level pruning with exact-dmin refinement.
//  - 64 groups of 8 samples; LDS: SoA pairs + per-group AABB + 2 reps.
//  - A-phase (lane i = group i): ub = min dist(rect_center, reps) + halfdiag
//    (wave-uniform upper bound on every lane's dmin); mask1 = ballot(AABB
//    dist < ub + MARGIN).
//  - S1 (VALU-only, mask1): exact per-lane d2min via u = |P|^2 - 2 g.P.
//    Nearest group is always in mask1 -> dmin exact.
//  - mask2 = ballot(AABB dist < wave_max(dmin) + MARGIN)  -- much tighter
//    radius than mask1 (dmax-dmin <= rect spread ~0.03 vs rep slack ~0.1).
//  - S2 (trans-heavy, mask2 only): s = sum 2^(C2*(dmin - d)); per-lane exact
//    bias -> terms <= 1, s >= 1. Skipped groups: every point >= dmin+MARGIN
//    for every lane -> per-term <= 2^-18.5, total effect <~3e-4 on output.

#define SIZE    512
#define NPAIRS  256
#define NGRP    64
#define MARGIN  0.05f
#define LOG2E   1.4426950408889634f
#define C2      (256.0f * LOG2E)

typedef float v2f __attribute__((ext_vector_type(2)));
typedef float v4f __attribute__((ext_vector_type(4)));

__device__ __forceinline__ float sqrt_raw(float x) { return __builtin_amdgcn_sqrtf(x); }
__device__ __forceinline__ float exp2_raw(float x) { return __builtin_amdgcn_exp2f(x); }
__device__ __forceinline__ float log2_raw(float x) { return __builtin_amdgcn_logf(x); }
__device__ __forceinline__ float rcp_raw(float x)  { return __builtin_amdgcn_rcpf(x); }
__device__ __forceinline__ float clamp01(float x)  { return fminf(fmaxf(x, 0.0f), 1.0f); }

__global__ __launch_bounds__(256) void bezier_glyph_kernel(
    const float* __restrict__ cp,      // (16,4,2)
    const float* __restrict__ grid,    // (NPIX,2)
    float* __restrict__ out)           // (NPIX,)
{
    __shared__ v4f sxy[NPAIRS];        // {x0,x1,y0,y1} per pair
    __shared__ v2f sp2[NPAIRS];        // {|P0|^2,|P1|^2} per pair
    __shared__ v4f sbox[NGRP];         // {lo.x, lo.y, hi.x, hi.y}
    __shared__ v4f srep[NGRP];         // {r1.x, r1.y, r2.x, r2.y} (samples 8g+2, 8g+6)

    const int tid = threadIdx.x;

    // --- stage 1a: one sample pair per thread ---
    {
        float px[2], py[2], pq[2];
#pragma unroll
        for (int k = 0; k < 2; ++k) {
            const int i = 2 * tid + k;
            const int stroke = i >> 5, samp = i & 31;
            const float t  = (float)samp * (1.0f / 31.0f);
            const float mt = 1.0f - t;
            const float b0 = mt * mt * mt;
            const float b1 = 3.0f * mt * mt * t;
            const float b2 = 3.0f * mt * t * t;
            const float b3 = t * t * t;
            const float* p = cp + stroke * 8;
            px[k] = b0 * clamp01(p[0]) + b1 * clamp01(p[2]) + b2 * clamp01(p[4]) + b3 * clamp01(p[6]);
            py[k] = b0 * clamp01(p[1]) + b1 * clamp01(p[3]) + b2 * clamp01(p[5]) + b3 * clamp01(p[7]);
            pq[k] = px[k] * px[k] + py[k] * py[k];
        }
        sxy[tid] = (v4f){px[0], px[1], py[0], py[1]};
        sp2[tid] = (v2f){pq[0], pq[1]};
    }
    __syncthreads();

    // --- stage 1b: per-group AABB + 2 reps (threads 0..63) ---
    if (tid < NGRP) {
        float lox = 1e30f, loy = 1e30f, hix = -1e30f, hiy = -1e30f;
#pragma unroll
        for (int k = 0; k < 4; ++k) {
            const v4f a = sxy[(tid << 2) + k];
            lox = fminf(lox, fminf(a.x, a.y));
            hix = fmaxf(hix, fmaxf(a.x, a.y));
            loy = fminf(loy, fminf(a.z, a.w));
            hiy = fmaxf(hiy, fmaxf(a.z, a.w));
        }
        sbox[tid] = (v4f){lox, loy, hix, hiy};
        const v4f a1 = sxy[(tid << 2) + 1];     // samples 8g+2, 8g+3
        const v4f a3 = sxy[(tid << 2) + 3];     // samples 8g+6, 8g+7
        srep[tid] = (v4f){a1.x, a1.z, a3.x, a3.z};
    }
    __syncthreads();

    // --- pixel mapping: 16x16 tile per block; wave = 16x4 rect ---
    const int lane = tid & 63;
    const int wv   = tid >> 6;                 // 0..3
    const int x = (blockIdx.x << 4) + (tid & 15);
    const int y = (blockIdx.y << 4) + (tid >> 4);
    const float2 g = reinterpret_cast<const float2*>(grid)[y * SIZE + x];

    // wave rect in grid coords (linspace(0,1,512)[i] = i/511; ulp slack
    // absorbed by MARGIN)
    const float inv511 = 1.0f / 511.0f;
    const float rx0 = (float)(blockIdx.x << 4) * inv511;
    const float rx1 = (float)((blockIdx.x << 4) + 15) * inv511;
    const float ry0 = (float)((blockIdx.y << 4) + (wv << 2)) * inv511;
    const float ry1 = (float)((blockIdx.y << 4) + (wv << 2) + 3) * inv511;
    const float cxr = 0.5f * (rx0 + rx1);
    const float cyr = 0.5f * (ry0 + ry1);
    const float hdx = 0.5f * (rx1 - rx0), hdy = 0.5f * (ry1 - ry0);
    const float hd  = sqrt_raw(hdx * hdx + hdy * hdy);   // ~0.0165

    // --- A-phase: lane i evaluates group i ---
    float dc, db2;
    {
        const v4f r = srep[lane];
        const float d1x = cxr - r.x, d1y = cyr - r.y;
        const float d2x = cxr - r.z, d2y = cyr - r.w;
        const float dd1 = d1x * d1x + d1y * d1y;
        const float dd2 = d2x * d2x + d2y * d2y;
        dc = sqrt_raw(fminf(dd1, dd2));
        const v4f b = sbox[lane];
        const float bdx = fmaxf(fmaxf(b.x - rx1, rx0 - b.z), 0.0f);
        const float bdy = fmaxf(fmaxf(b.y - ry1, ry0 - b.w), 0.0f);
        db2 = bdx * bdx + bdy * bdy;
    }
    // wave-min reduce of dc -> wave-uniform ub >= every lane's dmin
    float mdc = dc;
#pragma unroll
    for (int s = 1; s < 64; s <<= 1) mdc = fminf(mdc, __shfl_xor(mdc, s));
    const float ub   = mdc + hd;
    const float tau1 = ub + MARGIN;
    const unsigned long long mask1 = __ballot(db2 < tau1 * tau1);

    const float n2gx = -2.0f * g.x;
    const float n2gy = -2.0f * g.y;
    const float g2   = g.x * g.x + g.y * g.y;
    const v2f   g2v  = {g2, g2};

    // --- S1 (VALU-only): exact per-lane d2min over mask1 ---
    float m0 = 1e30f, m1 = 1e30f;
    {
        unsigned long long mm = mask1;
        while (mm) {
            const int gi = __ffsll(mm) - 1;
            mm &= mm - 1;
            const int base = gi << 2;
#pragma unroll
            for (int k = 0; k < 4; ++k) {
                const v4f a = sxy[base + k];
                const v2f q = sp2[base + k];
                const v2f u = (v2f){a.x, a.y} * n2gx + ((v2f){a.z, a.w} * n2gy + q);
                m0 = fminf(m0, u.x);
                m1 = fminf(m1, u.y);
            }
        }
    }
    const float d2min = fmaxf(fminf(m0, m1) + g2, 0.0f);
    const float dmin  = sqrt_raw(d2min);       // exact (nearest group in mask1)
    const float bias  = C2 * dmin;             // per-lane exact bias

    // --- tight mask2: radius dmax + MARGIN (dmax-dmin <= rect spread) ---
    float dmax = dmin;
#pragma unroll
    for (int s = 1; s < 64; s <<= 1) dmax = fmaxf(dmax, __shfl_xor(dmax, s));
    const float tau2 = dmax + MARGIN;
    const unsigned long long mask2 = __ballot(db2 < tau2 * tau2);

    // --- S2 (trans): s = sum 2^(C2*(dmin - d)) over mask2 ---
    float s0 = 0.0f, s1 = 0.0f;
    {
        unsigned long long mm = mask2;
        while (mm) {
            const int gi = __ffsll(mm) - 1;
            mm &= mm - 1;
            const int base = gi << 2;
#pragma unroll
            for (int k = 0; k < 4; ++k) {
                const v4f a = sxy[base + k];
                const v2f q = sp2[base + k];
                const v2f u = (v2f){a.x, a.y} * n2gx + ((v2f){a.z, a.w} * n2gy + q);
                const v2f d2v = u + g2v;
                const float da = sqrt_raw(fmaxf(d2v.x, 0.0f));
                const float db = sqrt_raw(fmaxf(d2v.y, 0.0f));
                s0 += exp2_raw(__builtin_fmaf(-C2, da, bias));
                s1 += exp2_raw(__builtin_fmaf(-C2, db, bias));
            }
        }
    }
    const float s = s0 + s1;                   // >= 1 (argmin point in mask2)

    const float min_dist = dmin - log2_raw(s) * (1.0f / C2);
    const float z  = (0.04f - min_dist) * 200.0f;
    const float ez = exp2_raw(z * LOG2E);
    out[y * SIZE + x] = rcp_raw(1.0f + ez);
}

extern "C" void kernel_launch(void* const* d_in, const int* in_sizes, int n_in,
                              void* d_out, int out_size, void* d_ws, size_t ws_size,
                              hipStream_t stream) {
    const float* cp   = (const float*)d_in[0];
    const float* grid = (const float*)d_in[1];
    float* out = (float*)d_out;

    dim3 grid_dim(SIZE / 16, SIZE / 16);
    bezier_glyph_kernel<<<grid_dim, 256, 0, stream>>>(cp, grid, out);
}

// Round 6
// 63.623 us; speedup vs baseline: 1.0383x; 1.0383x over previous
//
#include <hip/hip_runtime.h>

// BezierGlyph: 512x512 pixels vs 512 bezier samples (16 strokes x 32).
// min_dist = -LSE(-256*d)/256 ; out = 1/(1+exp((0.04-min_dist)*200))
//
// v6: wave fast path + single pruned S-loop + 8x8 wave rects.
//  - 64 groups of 8 samples; LDS: SoA pairs + per-group AABB + 2 reps.
//  - Each wave owns an 8x8 pixel rect (hd ~ 0.0097).
//  - FAST PATH: lb = wave-min rect-to-AABB distance. If lb > 0.095 then for
//    every pixel min_dist >= lb - log(512)/256 > 0.0706 -> z < -6.1 ->
//    |1 - out| < 2.3e-3: write 1.0, wave exits. (Samples live in the
//    control-point hull in [0.2,0.8]^2 -> ~half the image is far.)
//  - ub = min dist(rect_center, 2 reps/group) + hd  (wave-uniform, >= every
//    lane's dmin); mask = ballot(AABB dist < ub + MARGIN).
//  - S: s = sum 2^(C2*(ub - d)) over mask; min_dist = ub - log2(s)/C2 (exact
//    for any bias; ub >= dmin -> s >= 1; ub-dmin <= ~0.07 -> terms <= 2^26,
//    no overflow). Skipped groups: >= dmin+MARGIN for all lanes -> per-term
//    <= 2^-18.5 -> <=3e-4 on output.

#define SIZE    512
#define NPAIRS  256
#define NGRP    64
#define MARGIN  0.05f
#define LOG2E   1.4426950408889634f
#define C2      (256.0f * LOG2E)
#define FART2   0.009025f    // 0.095^2 far-skip threshold (squared)

typedef float v2f __attribute__((ext_vector_type(2)));
typedef float v4f __attribute__((ext_vector_type(4)));

__device__ __forceinline__ float sqrt_raw(float x) { return __builtin_amdgcn_sqrtf(x); }
__device__ __forceinline__ float exp2_raw(float x) { return __builtin_amdgcn_exp2f(x); }
__device__ __forceinline__ float log2_raw(float x) { return __builtin_amdgcn_logf(x); }
__device__ __forceinline__ float rcp_raw(float x)  { return __builtin_amdgcn_rcpf(x); }
__device__ __forceinline__ float clamp01(float x)  { return fminf(fmaxf(x, 0.0f), 1.0f); }

__global__ __launch_bounds__(256) void bezier_glyph_kernel(
    const float* __restrict__ cp,      // (16,4,2)
    const float* __restrict__ grid,    // (NPIX,2)
    float* __restrict__ out)           // (NPIX,)
{
    __shared__ v4f sxy[NPAIRS];        // {x0,x1,y0,y1} per pair
    __shared__ v2f sp2[NPAIRS];        // {|P0|^2,|P1|^2} per pair
    __shared__ v4f sbox[NGRP];         // {lo.x, lo.y, hi.x, hi.y}
    __shared__ v4f srep[NGRP];         // {r1.x, r1.y, r2.x, r2.y} (samples 8g+2, 8g+6)

    const int tid = threadIdx.x;

    // --- stage 1a: one sample pair per thread ---
    {
        float px[2], py[2], pq[2];
#pragma unroll
        for (int k = 0; k < 2; ++k) {
            const int i = 2 * tid + k;
            const int stroke = i >> 5, samp = i & 31;
            const float t  = (float)samp * (1.0f / 31.0f);
            const float mt = 1.0f - t;
            const float b0 = mt * mt * mt;
            const float b1 = 3.0f * mt * mt * t;
            const float b2 = 3.0f * mt * t * t;
            const float b3 = t * t * t;
            const float* p = cp + stroke * 8;
            px[k] = b0 * clamp01(p[0]) + b1 * clamp01(p[2]) + b2 * clamp01(p[4]) + b3 * clamp01(p[6]);
            py[k] = b0 * clamp01(p[1]) + b1 * clamp01(p[3]) + b2 * clamp01(p[5]) + b3 * clamp01(p[7]);
            pq[k] = px[k] * px[k] + py[k] * py[k];
        }
        sxy[tid] = (v4f){px[0], px[1], py[0], py[1]};
        sp2[tid] = (v2f){pq[0], pq[1]};
    }
    __syncthreads();

    // --- stage 1b: per-group AABB + 2 reps (threads 0..63) ---
    if (tid < NGRP) {
        float lox = 1e30f, loy = 1e30f, hix = -1e30f, hiy = -1e30f;
#pragma unroll
        for (int k = 0; k < 4; ++k) {
            const v4f a = sxy[(tid << 2) + k];
            lox = fminf(lox, fminf(a.x, a.y));
            hix = fmaxf(hix, fmaxf(a.x, a.y));
            loy = fminf(loy, fminf(a.z, a.w));
            hiy = fmaxf(hiy, fmaxf(a.z, a.w));
        }
        sbox[tid] = (v4f){lox, loy, hix, hiy};
        const v4f a1 = sxy[(tid << 2) + 1];     // samples 8g+2, 8g+3
        const v4f a3 = sxy[(tid << 2) + 3];     // samples 8g+6, 8g+7
        srep[tid] = (v4f){a1.x, a1.z, a3.x, a3.z};
    }
    __syncthreads();
    // NOTE: no barriers below this point -> wave-level early exit is safe.

    // --- pixel mapping: 16x16 tile per block; wave = 8x8 rect ---
    const int lane = tid & 63;
    const int wv   = tid >> 6;                  // 0..3 -> 2x2 sub-rects
    const int px0 = (blockIdx.x << 4) + ((wv & 1) << 3);
    const int py0 = (blockIdx.y << 4) + ((wv & 2) << 2);
    const int x = px0 + (lane & 7);
    const int y = py0 + (lane >> 3);
    const float2 g = reinterpret_cast<const float2*>(grid)[y * SIZE + x];

    // wave rect in grid coords (linspace(0,1,512)[i] = i/511; ulp slack
    // absorbed by MARGIN / fast-path slack)
    const float inv511 = 1.0f / 511.0f;
    const float rx0 = (float)px0 * inv511, rx1 = (float)(px0 + 7) * inv511;
    const float ry0 = (float)py0 * inv511, ry1 = (float)(py0 + 7) * inv511;
    const float cxr = 0.5f * (rx0 + rx1);
    const float cyr = 0.5f * (ry0 + ry1);
    const float hd  = 0.009686f;                // sqrt(2) * 3.5/511

    // --- A-phase: lane i evaluates group i ---
    const v4f b = sbox[lane];
    const float bdx = fmaxf(fmaxf(b.x - rx1, rx0 - b.z), 0.0f);   // v_max3
    const float bdy = fmaxf(fmaxf(b.y - ry1, ry0 - b.w), 0.0f);
    const float db2 = bdx * bdx + bdy * bdy;

    // fast path: wave-min rect-to-box distance
    float mdb = db2;
#pragma unroll
    for (int s = 1; s < 64; s <<= 1) mdb = fminf(mdb, __shfl_xor(mdb, s));
    if (mdb > FART2) {                          // wave-uniform
        out[y * SIZE + x] = 1.0f;
        return;
    }

    // upper bound via 2 reps per group
    const v4f r = srep[lane];
    const float d1x = cxr - r.x, d1y = cyr - r.y;
    const float d2x = cxr - r.z, d2y = cyr - r.w;
    float dc = sqrt_raw(fminf(d1x * d1x + d1y * d1y, d2x * d2x + d2y * d2y));
#pragma unroll
    for (int s = 1; s < 64; s <<= 1) dc = fminf(dc, __shfl_xor(dc, s));
    const float ub  = dc + hd;                  // wave-uniform, >= every lane's dmin
    const float tau = ub + MARGIN;
    const unsigned long long mask = __ballot(db2 < tau * tau);

    const float n2gx = -2.0f * g.x;
    const float n2gy = -2.0f * g.y;
    const float g2   = g.x * g.x + g.y * g.y;
    const v2f   g2v  = {g2, g2};
    const float bias = C2 * ub;

    // --- S: s = sum 2^(C2*(ub - d)) over survivor groups ---
    float s0 = 0.0f, s1 = 0.0f;
    {
        unsigned long long mm = mask;
        while (mm) {
            const int gi = __ffsll(mm) - 1;
            mm &= mm - 1;
            const int base = gi << 2;
#pragma unroll
            for (int k = 0; k < 4; ++k) {
                const v4f a = sxy[base + k];
                const v2f q = sp2[base + k];
                const v2f u = (v2f){a.x, a.y} * n2gx + ((v2f){a.z, a.w} * n2gy + q);
                const v2f d2v = u + g2v;
                const float da = sqrt_raw(fmaxf(d2v.x, 0.0f));
                const float db = sqrt_raw(fmaxf(d2v.y, 0.0f));
                s0 += exp2_raw(__builtin_fmaf(-C2, da, bias));
                s1 += exp2_raw(__builtin_fmaf(-C2, db, bias));
            }
        }
    }
    const float s = s0 + s1;                    // >= 1 (nearest group survives)

    const float min_dist = ub - log2_raw(s) * (1.0f / C2);
    const float z  = (0.04f - min_dist) * 200.0f;
    const float ez = exp2_raw(z * LOG2E);
    out[y * SIZE + x] = rcp_raw(1.0f + ez);
}

extern "C" void kernel_launch(void* const* d_in, const int* in_sizes, int n_in,
                              void* d_out, int out_size, void* d_ws, size_t ws_size,
                              hipStream_t stream) {
    const float* cp   = (const float*)d_in[0];
    const float* grid = (const float*)d_in[1];
    float* out = (float*)d_out;

    dim3 grid_dim(SIZE / 16, SIZE / 16);
    bezier_glyph_kernel<<<grid_dim, 256, 0, stream>>>(cp, grid, out);
}

// Round 7
// 62.442 us; speedup vs baseline: 1.0579x; 1.0189x over previous
//
#include <hip/hip_runtime.h>

// BezierGlyph: 512x512 pixels vs 512 bezier samples (16 strokes x 32).
// min_dist = -LSE(-256*d)/256 ; out = 1/(1+exp((0.04-min_dist)*200))
//
// v7: load-balanced scattered wave->rect mapping + 128 fine groups.
//  - 4096 8x8-pixel rects; wave (block b, wave w) -> rect ((w*1024+b)*2897)&4095
//    (odd-multiplier bijection). Scatters heavy near-curve rects uniformly
//    across blocks/CUs -> worst-CU ~ average-CU.
//  - 128 groups of 4 samples: tighter AABBs -> fewer survivor points.
//    Lane i owns groups i and i+64 (two 64-bit ballot masks).
//  - FAST PATH: lb = wave-min rect-to-box dist; lb > 0.095 -> min_dist >
//    0.0706 for every pixel -> 1-out < 2.3e-3: write 1.0, exit.
//  - ub = min dist(rect_center, 2 reps/group) + hd (wave-uniform >= dmin);
//    mask = ballot(box dist < ub + MARGIN). Skipped: every point >=
//    dmin+MARGIN for all lanes -> per-term <= 2^-18.5 -> <=3e-4 on output.
//  - s = sum 2^(C2*(ub-d)); min_dist = ub - log2(s)/C2 (exact for any bias;
//    ub >= dmin -> s >= 1; exponents <= C2*(hd+slack) ~ 2^13, no overflow).

#define SIZE    512
#define NPAIRS  256
#define NGRP    128          // groups of 4 samples (2 pairs)
#define MARGIN  0.05f
#define LOG2E   1.4426950408889634f
#define C2      (256.0f * LOG2E)
#define FART2   0.009025f    // 0.095^2

typedef float v2f __attribute__((ext_vector_type(2)));
typedef float v4f __attribute__((ext_vector_type(4)));

__device__ __forceinline__ float sqrt_raw(float x) { return __builtin_amdgcn_sqrtf(x); }
__device__ __forceinline__ float exp2_raw(float x) { return __builtin_amdgcn_exp2f(x); }
__device__ __forceinline__ float log2_raw(float x) { return __builtin_amdgcn_logf(x); }
__device__ __forceinline__ float rcp_raw(float x)  { return __builtin_amdgcn_rcpf(x); }
__device__ __forceinline__ float clamp01(float x)  { return fminf(fmaxf(x, 0.0f), 1.0f); }

__global__ __launch_bounds__(256) void bezier_glyph_kernel(
    const float* __restrict__ cp,      // (16,4,2)
    const float* __restrict__ grid,    // (NPIX,2)
    float* __restrict__ out)           // (NPIX,)
{
    __shared__ v4f sxy[NPAIRS];        // {x0,x1,y0,y1} per pair
    __shared__ v2f sp2[NPAIRS];        // {|P0|^2,|P1|^2} per pair
    __shared__ v4f sbox[NGRP];         // {lo.x, lo.y, hi.x, hi.y}
    __shared__ v4f srep[NGRP];         // {r1.x, r1.y, r2.x, r2.y} (samples 4g+1, 4g+2)

    const int tid = threadIdx.x;

    // --- stage 1a: one sample pair per thread ---
    {
        float px[2], py[2], pq[2];
#pragma unroll
        for (int k = 0; k < 2; ++k) {
            const int i = 2 * tid + k;
            const int stroke = i >> 5, samp = i & 31;
            const float t  = (float)samp * (1.0f / 31.0f);
            const float mt = 1.0f - t;
            const float b0 = mt * mt * mt;
            const float b1 = 3.0f * mt * mt * t;
            const float b2 = 3.0f * mt * t * t;
            const float b3 = t * t * t;
            const float* p = cp + stroke * 8;
            px[k] = b0 * clamp01(p[0]) + b1 * clamp01(p[2]) + b2 * clamp01(p[4]) + b3 * clamp01(p[6]);
            py[k] = b0 * clamp01(p[1]) + b1 * clamp01(p[3]) + b2 * clamp01(p[5]) + b3 * clamp01(p[7]);
            pq[k] = px[k] * px[k] + py[k] * py[k];
        }
        sxy[tid] = (v4f){px[0], px[1], py[0], py[1]};
        sp2[tid] = (v2f){pq[0], pq[1]};
    }
    __syncthreads();

    // --- stage 1b: group AABB + 2 reps (threads 0..127; group g = pairs 2g,2g+1) ---
    if (tid < NGRP) {
        const v4f a0 = sxy[2 * tid];          // samples 4g, 4g+1
        const v4f a1 = sxy[2 * tid + 1];      // samples 4g+2, 4g+3
        const float lox = fminf(fminf(a0.x, a0.y), fminf(a1.x, a1.y));
        const float hix = fmaxf(fmaxf(a0.x, a0.y), fmaxf(a1.x, a1.y));
        const float loy = fminf(fminf(a0.z, a0.w), fminf(a1.z, a1.w));
        const float hiy = fmaxf(fmaxf(a0.z, a0.w), fmaxf(a1.z, a1.w));
        sbox[tid] = (v4f){lox, loy, hix, hiy};
        srep[tid] = (v4f){a0.y, a0.w, a1.x, a1.z};   // samples 4g+1, 4g+2
    }
    __syncthreads();
    // NOTE: no barriers below -> wave-level early exit is safe.

    // --- scattered wave->rect mapping ---
    const int lane = tid & 63;
    const int wv   = tid >> 6;
    const int rect = ((wv << 10 | blockIdx.x) * 2897) & 4095;  // bijection
    const int px0 = (rect & 63) << 3;
    const int py0 = (rect >> 6) << 3;
    const int x = px0 + (lane & 7);
    const int y = py0 + (lane >> 3);

    const float inv511 = 1.0f / 511.0f;
    const float rx0 = (float)px0 * inv511, rx1 = (float)(px0 + 7) * inv511;
    const float ry0 = (float)py0 * inv511, ry1 = (float)(py0 + 7) * inv511;
    const float cxr = 0.5f * (rx0 + rx1);
    const float cyr = 0.5f * (ry0 + ry1);
    const float hd  = 0.009686f;               // sqrt(2)*3.5/511

    // --- A-phase: lane i owns groups i and i+64 ---
    const v4f b0 = sbox[lane];
    const v4f b1 = sbox[lane + 64];
    const float bdx0 = fmaxf(fmaxf(b0.x - rx1, rx0 - b0.z), 0.0f);
    const float bdy0 = fmaxf(fmaxf(b0.y - ry1, ry0 - b0.w), 0.0f);
    const float db2_0 = bdx0 * bdx0 + bdy0 * bdy0;
    const float bdx1 = fmaxf(fmaxf(b1.x - rx1, rx0 - b1.z), 0.0f);
    const float bdy1 = fmaxf(fmaxf(b1.y - ry1, ry0 - b1.w), 0.0f);
    const float db2_1 = bdx1 * bdx1 + bdy1 * bdy1;

    // fast path: wave-min rect-to-box distance (lower bound on every dmin)
    float mdb = fminf(db2_0, db2_1);
#pragma unroll
    for (int s = 1; s < 64; s <<= 1) mdb = fminf(mdb, __shfl_xor(mdb, s));
    if (mdb > FART2) {
        out[y * SIZE + x] = 1.0f;
        return;
    }

    // upper bound: min dist(center, reps) over all 128 groups
    const v4f r0 = srep[lane];
    const v4f r1 = srep[lane + 64];
    float dr;
    {
        const float e0x = cxr - r0.x, e0y = cyr - r0.y;
        const float e1x = cxr - r0.z, e1y = cyr - r0.w;
        const float e2x = cxr - r1.x, e2y = cyr - r1.y;
        const float e3x = cxr - r1.z, e3y = cyr - r1.w;
        dr = fminf(fminf(e0x * e0x + e0y * e0y, e1x * e1x + e1y * e1y),
                   fminf(e2x * e2x + e2y * e2y, e3x * e3x + e3y * e3y));
    }
    float dc = sqrt_raw(dr);
#pragma unroll
    for (int s = 1; s < 64; s <<= 1) dc = fminf(dc, __shfl_xor(dc, s));
    const float ub  = dc + hd;                 // wave-uniform, >= every lane's dmin
    const float tau = ub + MARGIN;
    const float tau2 = tau * tau;
    const unsigned long long mask_lo = __ballot(db2_0 < tau2);
    const unsigned long long mask_hi = __ballot(db2_1 < tau2);

    const float2 g = reinterpret_cast<const float2*>(grid)[y * SIZE + x];
    const float n2gx = -2.0f * g.x;
    const float n2gy = -2.0f * g.y;
    const float g2   = g.x * g.x + g.y * g.y;
    const v2f   g2v  = {g2, g2};
    const float bias = C2 * ub;

    // --- S: s = sum 2^(C2*(ub - d)) over survivor groups (2 pairs each) ---
    float s0 = 0.0f, s1 = 0.0f;
#pragma unroll
    for (int h = 0; h < 2; ++h) {
        unsigned long long mm = h ? mask_hi : mask_lo;
        const int goff = h << 6;
        while (mm) {
            const int gi = __ffsll(mm) - 1;
            mm &= mm - 1;
            const int base = (goff + gi) << 1;
#pragma unroll
            for (int k = 0; k < 2; ++k) {
                const v4f a = sxy[base + k];
                const v2f q = sp2[base + k];
                const v2f u = (v2f){a.x, a.y} * n2gx + ((v2f){a.z, a.w} * n2gy + q);
                const v2f d2v = u + g2v;
                const float da = sqrt_raw(fmaxf(d2v.x, 0.0f));
                const float db = sqrt_raw(fmaxf(d2v.y, 0.0f));
                s0 += exp2_raw(__builtin_fmaf(-C2, da, bias));
                s1 += exp2_raw(__builtin_fmaf(-C2, db, bias));
            }
        }
    }
    const float s = s0 + s1;                   // >= 1 (nearest group survives)

    const float min_dist = ub - log2_raw(s) * (1.0f / C2);
    const float z  = (0.04f - min_dist) * 200.0f;
    const float ez = exp2_raw(z * LOG2E);
    out[y * SIZE + x] = rcp_raw(1.0f + ez);
}

extern "C" void kernel_launch(void* const* d_in, const int* in_sizes, int n_in,
                              void* d_out, int out_size, void* d_ws, size_t ws_size,
                              hipStream_t stream) {
    const float* cp   = (const float*)d_in[0];
    const float* grid = (const float*)d_in[1];
    float* out = (float*)d_out;

    bezier_glyph_kernel<<<1024, 256, 0, stream>>>(cp, grid, out);
}

// Round 8
// 61.681 us; speedup vs baseline: 1.0709x; 1.0123x over previous
//
#include <hip/hip_runtime.h>

// BezierGlyph: 512x512 pixels vs 512 bezier samples (16 strokes x 32).
// min_dist = -LSE(-256*d)/256 ; out = 1/(1+exp((0.04-min_dist)*200))
//
// v8: occupancy/latency attack.
//  - 1024 blocks x 512 threads = 8192 waves = 32 waves/CU (2x v7's residency;
//    v7 evidence says the kernel is latency-bound, not issue-bound).
//  - Each wave owns an 8x4 pixel rect; lane pair (2k,2k+1) shares pixel k.
//    Even lane processes even-indexed survivor groups, odd lane odd-indexed
//    (adjacent curve groups alternate parity -> balanced). s combined with
//    one shfl_xor(1). Halves each lane's serial LDS->trans->acc chain.
//  - Same pruning as v7: 128 groups of 4 samples, AABB + 2 reps in LDS;
//    fast path (wave-min rect-to-box dist > 0.095 -> out=1, error <2.3e-3);
//    ub = min dist(center, reps) + hd (wave-uniform >= every lane's dmin);
//    mask = ballot(box dist < ub + MARGIN); skipped terms <= 2^-18.5 each.
//  - s = sum 2^(C2*(ub-d)); min_dist = ub - log2(s)/C2 (exact for any bias).

#define SIZE    512
#define NPAIRS  256
#define NGRP    128          // groups of 4 samples (2 pairs)
#define BLOCK   512
#define MARGIN  0.05f
#define LOG2E   1.4426950408889634f
#define C2      (256.0f * LOG2E)
#define FART2   0.009025f    // 0.095^2
#define EVENM   0x5555555555555555ull

typedef float v2f __attribute__((ext_vector_type(2)));
typedef float v4f __attribute__((ext_vector_type(4)));

__device__ __forceinline__ float sqrt_raw(float x) { return __builtin_amdgcn_sqrtf(x); }
__device__ __forceinline__ float exp2_raw(float x) { return __builtin_amdgcn_exp2f(x); }
__device__ __forceinline__ float log2_raw(float x) { return __builtin_amdgcn_logf(x); }
__device__ __forceinline__ float rcp_raw(float x)  { return __builtin_amdgcn_rcpf(x); }
__device__ __forceinline__ float clamp01(float x)  { return fminf(fmaxf(x, 0.0f), 1.0f); }

__global__ __launch_bounds__(BLOCK) void bezier_glyph_kernel(
    const float* __restrict__ cp,      // (16,4,2)
    const float* __restrict__ grid,    // (NPIX,2)
    float* __restrict__ out)           // (NPIX,)
{
    __shared__ v4f sxy[NPAIRS];        // {x0,x1,y0,y1} per pair
    __shared__ v2f sp2[NPAIRS];        // {|P0|^2,|P1|^2} per pair
    __shared__ v4f sbox[NGRP];         // {lo.x, lo.y, hi.x, hi.y}
    __shared__ v4f srep[NGRP];         // {r1.x, r1.y, r2.x, r2.y} (samples 4g+1, 4g+2)

    const int tid = threadIdx.x;

    // --- stage 1a: threads 0..255 build one sample pair each ---
    if (tid < NPAIRS) {
        float px[2], py[2], pq[2];
#pragma unroll
        for (int k = 0; k < 2; ++k) {
            const int i = 2 * tid + k;
            const int stroke = i >> 5, samp = i & 31;
            const float t  = (float)samp * (1.0f / 31.0f);
            const float mt = 1.0f - t;
            const float b0 = mt * mt * mt;
            const float b1 = 3.0f * mt * mt * t;
            const float b2 = 3.0f * mt * t * t;
            const float b3 = t * t * t;
            const float* p = cp + stroke * 8;
            px[k] = b0 * clamp01(p[0]) + b1 * clamp01(p[2]) + b2 * clamp01(p[4]) + b3 * clamp01(p[6]);
            py[k] = b0 * clamp01(p[1]) + b1 * clamp01(p[3]) + b2 * clamp01(p[5]) + b3 * clamp01(p[7]);
            pq[k] = px[k] * px[k] + py[k] * py[k];
        }
        sxy[tid] = (v4f){px[0], px[1], py[0], py[1]};
        sp2[tid] = (v2f){pq[0], pq[1]};
    }
    __syncthreads();

    // --- stage 1b: group AABB + 2 reps (threads 0..127; group g = pairs 2g,2g+1) ---
    if (tid < NGRP) {
        const v4f a0 = sxy[2 * tid];          // samples 4g, 4g+1
        const v4f a1 = sxy[2 * tid + 1];      // samples 4g+2, 4g+3
        const float lox = fminf(fminf(a0.x, a0.y), fminf(a1.x, a1.y));
        const float hix = fmaxf(fmaxf(a0.x, a0.y), fmaxf(a1.x, a1.y));
        const float loy = fminf(fminf(a0.z, a0.w), fminf(a1.z, a1.w));
        const float hiy = fmaxf(fmaxf(a0.z, a0.w), fmaxf(a1.z, a1.w));
        sbox[tid] = (v4f){lox, loy, hix, hiy};
        srep[tid] = (v4f){a0.y, a0.w, a1.x, a1.z};   // samples 4g+1, 4g+2
    }
    __syncthreads();
    // NOTE: no barriers below -> wave-level early exit is safe.

    // --- scattered wave->rect mapping: 8192 rects of 8x4 pixels ---
    const int lane   = tid & 63;
    const int parity = lane & 1;
    const int k      = lane >> 1;              // pixel 0..31 within rect
    const int wid    = (blockIdx.x << 3) | (tid >> 6);
    const int rect   = (wid * 2897) & 8191;    // odd-mult bijection
    const int px0 = (rect & 63) << 3;          // 64 cols of 8
    const int py0 = (rect >> 6) << 2;          // 128 rows of 4
    const int x = px0 + (k & 7);
    const int y = py0 + (k >> 3);

    const float inv511 = 1.0f / 511.0f;
    const float rx0 = (float)px0 * inv511, rx1 = (float)(px0 + 7) * inv511;
    const float ry0 = (float)py0 * inv511, ry1 = (float)(py0 + 3) * inv511;
    const float cxr = 0.5f * (rx0 + rx1);
    const float cyr = 0.5f * (ry0 + ry1);
    const float hd  = 0.007452f;               // sqrt(3.5^2+1.5^2)/511

    // --- A-phase: lane i owns groups i and i+64 ---
    const v4f b0 = sbox[lane];
    const v4f b1 = sbox[lane + 64];
    const float bdx0 = fmaxf(fmaxf(b0.x - rx1, rx0 - b0.z), 0.0f);
    const float bdy0 = fmaxf(fmaxf(b0.y - ry1, ry0 - b0.w), 0.0f);
    const float db2_0 = bdx0 * bdx0 + bdy0 * bdy0;
    const float bdx1 = fmaxf(fmaxf(b1.x - rx1, rx0 - b1.z), 0.0f);
    const float bdy1 = fmaxf(fmaxf(b1.y - ry1, ry0 - b1.w), 0.0f);
    const float db2_1 = bdx1 * bdx1 + bdy1 * bdy1;

    // fast path: wave-min rect-to-box distance (lower bound on every dmin)
    float mdb = fminf(db2_0, db2_1);
#pragma unroll
    for (int s = 1; s < 64; s <<= 1) mdb = fminf(mdb, __shfl_xor(mdb, s));
    if (mdb > FART2) {
        if (parity == 0) out[y * SIZE + x] = 1.0f;
        return;
    }

    // upper bound: min dist(center, reps) over all 128 groups
    const v4f r0 = srep[lane];
    const v4f r1 = srep[lane + 64];
    float dr;
    {
        const float e0x = cxr - r0.x, e0y = cyr - r0.y;
        const float e1x = cxr - r0.z, e1y = cyr - r0.w;
        const float e2x = cxr - r1.x, e2y = cyr - r1.y;
        const float e3x = cxr - r1.z, e3y = cyr - r1.w;
        dr = fminf(fminf(e0x * e0x + e0y * e0y, e1x * e1x + e1y * e1y),
                   fminf(e2x * e2x + e2y * e2y, e3x * e3x + e3y * e3y));
    }
    float dc = sqrt_raw(dr);
#pragma unroll
    for (int s = 1; s < 64; s <<= 1) dc = fminf(dc, __shfl_xor(dc, s));
    const float ub  = dc + hd;                 // wave-uniform, >= every lane's dmin
    const float tau = ub + MARGIN;
    const float tau2 = tau * tau;
    // per-parity split: even lane takes even-indexed groups, odd lane odd
    const unsigned long long pm = parity ? ~EVENM : EVENM;
    const unsigned long long mask_lo = __ballot(db2_0 < tau2) & pm;
    const unsigned long long mask_hi = __ballot(db2_1 < tau2) & pm;

    const float2 g = reinterpret_cast<const float2*>(grid)[y * SIZE + x];
    const float n2gx = -2.0f * g.x;
    const float n2gy = -2.0f * g.y;
    const float g2   = g.x * g.x + g.y * g.y;
    const v2f   g2v  = {g2, g2};
    const float bias = C2 * ub;

    // --- S: s = sum 2^(C2*(ub - d)) over this lane's survivor groups ---
    float s0 = 0.0f, s1 = 0.0f;
#pragma unroll
    for (int h = 0; h < 2; ++h) {
        unsigned long long mm = h ? mask_hi : mask_lo;
        const int goff = h << 6;
        while (mm) {
            const int gi = __ffsll(mm) - 1;
            mm &= mm - 1;
            const int base = (goff + gi) << 1;
#pragma unroll
            for (int kk = 0; kk < 2; ++kk) {
                const v4f a = sxy[base + kk];
                const v2f q = sp2[base + kk];
                const v2f u = (v2f){a.x, a.y} * n2gx + ((v2f){a.z, a.w} * n2gy + q);
                const v2f d2v = u + g2v;
                const float da = sqrt_raw(fmaxf(d2v.x, 0.0f));
                const float db = sqrt_raw(fmaxf(d2v.y, 0.0f));
                s0 += exp2_raw(__builtin_fmaf(-C2, da, bias));
                s1 += exp2_raw(__builtin_fmaf(-C2, db, bias));
            }
        }
    }
    // combine lane pair (same pixel): total s
    float s = s0 + s1;
    s += __shfl_xor(s, 1);                     // >= 1 (nearest group in union)

    const float min_dist = ub - log2_raw(s) * (1.0f / C2);
    const float z  = (0.04f - min_dist) * 200.0f;
    const float ez = exp2_raw(z * LOG2E);
    if (parity == 0) out[y * SIZE + x] = rcp_raw(1.0f + ez);
}

extern "C" void kernel_launch(void* const* d_in, const int* in_sizes, int n_in,
                              void* d_out, int out_size, void* d_ws, size_t ws_size,
                              hipStream_t stream) {
    const float* cp   = (const float*)d_in[0];
    const float* grid = (const float*)d_in[1];
    float* out = (float*)d_out;

    bezier_glyph_kernel<<<1024, BLOCK, 0, stream>>>(cp, grid, out);
}